// Round 1
// baseline (253.684 us; speedup 1.0000x reference)
//
#include <hip/hip_runtime.h>
#include <stdint.h>

#define MARGIN 0.3f

constexpr int N = 8192;
constexpr int D = 512;
constexpr int BM = 128, BN = 128, BK = 32;
constexpr int NSTRIP = 16;                    // j-strips per i-tile
constexpr int JT_PER_STRIP = N / BN / NSTRIP; // 4
constexpr int NTILES_I = N / BM;              // 64

typedef short bf16x8 __attribute__((ext_vector_type(8)));
typedef float f32x4 __attribute__((ext_vector_type(4)));

// monotone float<->ordered-int encoding (for atomicMin/Max on float values)
__device__ __forceinline__ int enc_f32(float f) {
  int b = __float_as_int(f);
  return b >= 0 ? b : (b ^ 0x7fffffff);
}
__device__ __forceinline__ float dec_f32(int k) {
  return __int_as_float(k >= 0 ? k : (k ^ 0x7fffffff));
}

__device__ __forceinline__ unsigned short f2bf(float f) {
  unsigned u = __float_as_uint(f);
  u += 0x7fffu + ((u >> 16) & 1u); // RNE
  return (unsigned short)(u >> 16);
}

__device__ __forceinline__ void load_lds16(const unsigned short* g, short* l) {
  __builtin_amdgcn_global_load_lds((const __attribute__((address_space(1))) void*)g,
                                   (__attribute__((address_space(3))) void*)l,
                                   16, 0, 0);
}

// ---- kernel 1: L2-normalize rows -> bf16; init min/max arrays ----
__global__ __launch_bounds__(256) void normalize_rows(
    const float* __restrict__ emb, unsigned short* __restrict__ e,
    int* __restrict__ minpos_enc, int* __restrict__ maxneg_enc) {
  const int wave = threadIdx.x >> 6, lane = threadIdx.x & 63;
  const int row = blockIdx.x * 4 + wave;
  const float4* src = (const float4*)(emb + (size_t)row * D);
  float4 x0 = src[lane];
  float4 x1 = src[lane + 64];
  float ss = x0.x * x0.x + x0.y * x0.y + x0.z * x0.z + x0.w * x0.w +
             x1.x * x1.x + x1.y * x1.y + x1.z * x1.z + x1.w * x1.w;
#pragma unroll
  for (int m = 1; m < 64; m <<= 1) ss += __shfl_xor(ss, m, 64);
  float r = rsqrtf(ss);
  ushort4 o0 = {f2bf(x0.x * r), f2bf(x0.y * r), f2bf(x0.z * r), f2bf(x0.w * r)};
  ushort4 o1 = {f2bf(x1.x * r), f2bf(x1.y * r), f2bf(x1.z * r), f2bf(x1.w * r)};
  ushort4* dst = (ushort4*)(e + (size_t)row * D);
  dst[lane] = o0;
  dst[lane + 64] = o1;
  if (lane == 0) {
    minpos_enc[row] = 0x7f800000;      // enc(+inf)
    maxneg_enc[row] = (int)0x807fffff; // enc(-inf)
  }
}

// ---- kernel 2: fused Gram-tile GEMM + batch-hard mining ----
__global__ __launch_bounds__(256) void bh_gemm(
    const unsigned short* __restrict__ e, const int* __restrict__ labels,
    int* __restrict__ minpos_enc, int* __restrict__ maxneg_enc) {
  __shared__ short As[BM * BK]; // [row][k], k contiguous (64B rows)
  __shared__ short Bs[BN * BK];

  const int tid = threadIdx.x;
  const int lane = tid & 63;
  const int wave = tid >> 6;
  const int wr = wave >> 1, wc = wave & 1;
  const int quad = lane >> 4, n16 = lane & 15;

  const int iTile = blockIdx.x / NSTRIP;
  const int strip = blockIdx.x % NSTRIP;
  const int iBase = iTile * BM;
  const int jBase0 = strip * (JT_PER_STRIP * BN);

  // labels for the 16 rows this lane accumulates (C/D layout: row=quad*4+v, col=n16)
  int li[16];
#pragma unroll
  for (int k = 0; k < 16; ++k) {
    int r = k >> 2, v = k & 3;
    li[k] = labels[iBase + wr * 64 + r * 16 + quad * 4 + v];
  }

  float minp[16], maxn[16];
#pragma unroll
  for (int k = 0; k < 16; ++k) {
    minp[k] = __builtin_inff();
    maxn[k] = -__builtin_inff();
  }

  for (int jt = 0; jt < JT_PER_STRIP; ++jt) {
    const int jBase = jBase0 + jt * BN;
    f32x4 acc[4][4];
#pragma unroll
    for (int r = 0; r < 4; ++r)
#pragma unroll
      for (int c = 0; c < 4; ++c) acc[r][c] = (f32x4)0.0f;

    for (int k0 = 0; k0 < D; k0 += BK) {
      __syncthreads(); // previous chunk's reads done before overwrite
#pragma unroll
      for (int it = 0; it < 2; ++it) {
        int q = it * 256 + tid; // 16B segment id; lds dest = uniform base + lane*16
        int row = q >> 2, seg = q & 3;
        load_lds16(e + (size_t)(iBase + row) * D + k0 + seg * 8, As + q * 8);
        load_lds16(e + (size_t)(jBase + row) * D + k0 + seg * 8, Bs + q * 8);
      }
      __syncthreads(); // drains vmcnt, staging visible

      bf16x8 af[4], bf[4];
#pragma unroll
      for (int r = 0; r < 4; ++r)
        af[r] = *(const bf16x8*)(As + (wr * 64 + r * 16 + n16) * BK + quad * 8);
#pragma unroll
      for (int c = 0; c < 4; ++c)
        bf[c] = *(const bf16x8*)(Bs + (wc * 64 + c * 16 + n16) * BK + quad * 8);
#pragma unroll
      for (int r = 0; r < 4; ++r)
#pragma unroll
        for (int c = 0; c < 4; ++c)
          acc[r][c] = __builtin_amdgcn_mfma_f32_16x16x32_bf16(af[r], bf[c], acc[r][c], 0, 0, 0);
    }

    // epilogue: masked running min/max (registers only)
    int lj[4];
#pragma unroll
    for (int c = 0; c < 4; ++c) lj[c] = labels[jBase + wc * 64 + c * 16 + n16];
    const bool isDiag = (jBase == iBase);
#pragma unroll
    for (int r = 0; r < 4; ++r) {
#pragma unroll
      for (int c = 0; c < 4; ++c) {
#pragma unroll
        for (int v = 0; v < 4; ++v) {
          float s = acc[r][c][v];
          bool same = (li[r * 4 + v] == lj[c]);
          float pv = same ? s : __builtin_inff();
          float nv = same ? -__builtin_inff() : s;
          if (isDiag) {
            int row_ = wr * 64 + r * 16 + quad * 4 + v;
            int col_ = wc * 64 + c * 16 + n16;
            if (row_ == col_) pv = __builtin_inff(); // exclude self from positives
          }
          minp[r * 4 + v] = fminf(minp[r * 4 + v], pv);
          maxn[r * 4 + v] = fmaxf(maxn[r * 4 + v], nv);
        }
      }
    }
  }

  // butterfly-reduce across the 16 lanes (n16) that share the same rows
#pragma unroll
  for (int m = 1; m <= 8; m <<= 1) {
#pragma unroll
    for (int k = 0; k < 16; ++k) {
      minp[k] = fminf(minp[k], __shfl_xor(minp[k], m, 64));
      maxn[k] = fmaxf(maxn[k], __shfl_xor(maxn[k], m, 64));
    }
  }
  if (n16 == 0) {
#pragma unroll
    for (int k = 0; k < 16; ++k) {
      int r = k >> 2, v = k & 3;
      int row = iBase + wr * 64 + r * 16 + quad * 4 + v;
      atomicMin(&minpos_enc[row], enc_f32(minp[k]));
      atomicMax(&maxneg_enc[row], enc_f32(maxn[k]));
    }
  }
}

// ---- kernel 3: loss = mean(relu(maxneg_s - minpos_s + margin)) ----
__global__ __launch_bounds__(256) void finalize_loss(
    const int* __restrict__ minpos_enc, const int* __restrict__ maxneg_enc,
    float* __restrict__ out) {
  const int tid = threadIdx.x;
  float sum = 0.f;
  for (int i = tid; i < N; i += 256) {
    float mp = dec_f32(minpos_enc[i]); // min positive similarity (+inf if none)
    float mn = dec_f32(maxneg_enc[i]); // max negative similarity
    float loss = mn - mp + MARGIN;     // == hardest_pos - hardest_neg + margin
    sum += loss > 0.f ? loss : 0.f;    // relu(-inf) = 0 matches jnp
  }
#pragma unroll
  for (int m = 1; m < 64; m <<= 1) sum += __shfl_xor(sum, m, 64);
  __shared__ float ws4[4];
  const int lane = tid & 63, wave = tid >> 6;
  if (lane == 0) ws4[wave] = sum;
  __syncthreads();
  if (tid == 0) out[0] = (ws4[0] + ws4[1] + ws4[2] + ws4[3]) * (1.0f / N);
}

extern "C" void kernel_launch(void* const* d_in, const int* in_sizes, int n_in,
                              void* d_out, int out_size, void* d_ws, size_t ws_size,
                              hipStream_t stream) {
  const float* emb = (const float*)d_in[0];
  const int* labels = (const int*)d_in[1];
  float* out = (float*)d_out;

  unsigned short* e = (unsigned short*)d_ws; // N*D bf16 = 8 MB
  int* minpos_enc = (int*)((char*)d_ws + (size_t)N * D * sizeof(unsigned short));
  int* maxneg_enc = minpos_enc + N;

  normalize_rows<<<N / 4, 256, 0, stream>>>(emb, e, minpos_enc, maxneg_enc);
  bh_gemm<<<NTILES_I * NSTRIP, 256, 0, stream>>>(e, labels, minpos_enc, maxneg_enc);
  finalize_loss<<<1, 256, 0, stream>>>(minpos_enc, maxneg_enc, out);
}

// Round 2
// 181.695 us; speedup vs baseline: 1.3962x; 1.3962x over previous
//
#include <hip/hip_runtime.h>
#include <stdint.h>

#define MARGIN 0.3f

constexpr int N = 8192;
constexpr int D = 512;
constexpr int BM = 128, BN = 128, BK = 32;
constexpr int NT = N / BM; // 64 tiles per side

typedef short bf16x8 __attribute__((ext_vector_type(8)));
typedef float f32x4 __attribute__((ext_vector_type(4)));

// monotone float<->ordered-int encoding (for atomicMin/Max on float values)
__device__ __forceinline__ int enc_f32(float f) {
  int b = __float_as_int(f);
  return b >= 0 ? b : (b ^ 0x7fffffff);
}
__device__ __forceinline__ float dec_f32(int k) {
  return __int_as_float(k >= 0 ? k : (k ^ 0x7fffffff));
}

__device__ __forceinline__ unsigned short f2bf(float f) {
  unsigned u = __float_as_uint(f);
  u += 0x7fffu + ((u >> 16) & 1u); // RNE
  return (unsigned short)(u >> 16);
}

__device__ __forceinline__ void load_lds16(const unsigned short* g, short* l) {
  __builtin_amdgcn_global_load_lds((const __attribute__((address_space(1))) void*)g,
                                   (__attribute__((address_space(3))) void*)l,
                                   16, 0, 0);
}

// ---- kernel 1: L2-normalize rows -> bf16; init min/max arrays ----
__global__ __launch_bounds__(256) void normalize_rows(
    const float* __restrict__ emb, unsigned short* __restrict__ e,
    int* __restrict__ minpos_enc, int* __restrict__ maxneg_enc) {
  const int wave = threadIdx.x >> 6, lane = threadIdx.x & 63;
  const int row = blockIdx.x * 4 + wave;
  const float4* src = (const float4*)(emb + (size_t)row * D);
  float4 x0 = src[lane];
  float4 x1 = src[lane + 64];
  float ss = x0.x * x0.x + x0.y * x0.y + x0.z * x0.z + x0.w * x0.w +
             x1.x * x1.x + x1.y * x1.y + x1.z * x1.z + x1.w * x1.w;
#pragma unroll
  for (int m = 1; m < 64; m <<= 1) ss += __shfl_xor(ss, m, 64);
  float r = rsqrtf(ss);
  ushort4 o0 = {f2bf(x0.x * r), f2bf(x0.y * r), f2bf(x0.z * r), f2bf(x0.w * r)};
  ushort4 o1 = {f2bf(x1.x * r), f2bf(x1.y * r), f2bf(x1.z * r), f2bf(x1.w * r)};
  ushort4* dst = (ushort4*)(e + (size_t)row * D);
  dst[lane] = o0;
  dst[lane + 64] = o1;
  if (lane == 0) {
    minpos_enc[row] = 0x7f800000;      // enc(+inf)
    maxneg_enc[row] = (int)0x807fffff; // enc(-inf)
  }
}

// ---- kernel 2: symmetric fused Gram-tile GEMM + batch-hard mining ----
// Grid: (64, 33); block (x,y) handles tile pair {ti=x, tj=(x+y)%64}.
// y==0 is the diagonal (self-exclusion, no transpose mining).
// y==32 pairs are generated twice; x>=32 half early-exits.
__global__ __launch_bounds__(256) void bh_gemm_sym(
    const unsigned short* __restrict__ e, const int* __restrict__ labels,
    int* __restrict__ minpos_enc, int* __restrict__ maxneg_enc) {
  __shared__ short As[BM * BK]; // [row][slot], slot = seg ^ ((row>>1)&3)
  __shared__ short Bs[BN * BK];

  const int x = blockIdx.x, y = blockIdx.y;
  if (y == 32 && x >= 32) return; // dedupe distance-32 pairs
  const int ti = x, tj = (x + y) & (NT - 1);
  const int iBase = ti * BM, jBase = tj * BN;
  const bool diag = (y == 0);

  const int tid = threadIdx.x;
  const int lane = tid & 63;
  const int wave = tid >> 6;
  const int wr = wave >> 1, wc = wave & 1;
  const int quad = lane >> 4, n16 = lane & 15;

  f32x4 acc[4][4];
#pragma unroll
  for (int r = 0; r < 4; ++r)
#pragma unroll
    for (int c = 0; c < 4; ++c) acc[r][c] = (f32x4)0.0f;

  for (int k0 = 0; k0 < D; k0 += BK) {
    __syncthreads(); // previous chunk's reads done before overwrite
#pragma unroll
    for (int it = 0; it < 2; ++it) {
      int q = it * 256 + tid; // LDS 16B-slot id; dest = uniform base + lane*16
      int row = q >> 2, pos = q & 3;
      int seg = pos ^ ((row >> 1) & 3); // bank-swizzle via global source addr
      load_lds16(e + (size_t)(iBase + row) * D + k0 + seg * 8, As + q * 8);
      load_lds16(e + (size_t)(jBase + row) * D + k0 + seg * 8, Bs + q * 8);
    }
    __syncthreads(); // drains vmcnt, staging visible

    bf16x8 af[4], bf[4];
#pragma unroll
    for (int r = 0; r < 4; ++r) {
      int rowa = wr * 64 + r * 16 + n16;
      af[r] = *(const bf16x8*)(As + rowa * BK + (quad ^ ((rowa >> 1) & 3)) * 8);
    }
#pragma unroll
    for (int c = 0; c < 4; ++c) {
      int rowb = wc * 64 + c * 16 + n16;
      bf[c] = *(const bf16x8*)(Bs + rowb * BK + (quad ^ ((rowb >> 1) & 3)) * 8);
    }
#pragma unroll
    for (int r = 0; r < 4; ++r)
#pragma unroll
      for (int c = 0; c < 4; ++c)
        acc[r][c] = __builtin_amdgcn_mfma_f32_16x16x32_bf16(af[r], bf[c], acc[r][c], 0, 0, 0);
  }

  // ---- epilogue: batch-hard mining, rows (and cols if off-diagonal) ----
  // C/D layout: row = wr*64 + r*16 + quad*4 + v, col = wc*64 + c*16 + n16
  int4 li4[4];
#pragma unroll
  for (int r = 0; r < 4; ++r)
    li4[r] = *(const int4*)(labels + iBase + wr * 64 + r * 16 + quad * 4);
  int lj[4];
#pragma unroll
  for (int c = 0; c < 4; ++c) lj[c] = labels[jBase + wc * 64 + c * 16 + n16];

  float minp[16], maxn[16], cminp[4], cmaxn[4];
#pragma unroll
  for (int k = 0; k < 16; ++k) {
    minp[k] = __builtin_inff();
    maxn[k] = -__builtin_inff();
  }
#pragma unroll
  for (int c = 0; c < 4; ++c) {
    cminp[c] = __builtin_inff();
    cmaxn[c] = -__builtin_inff();
  }

#pragma unroll
  for (int r = 0; r < 4; ++r) {
    const int* lav = (const int*)&li4[r];
#pragma unroll
    for (int c = 0; c < 4; ++c) {
#pragma unroll
      for (int v = 0; v < 4; ++v) {
        float s = acc[r][c][v];
        bool same = (lav[v] == lj[c]);
        float pv = same ? s : __builtin_inff();
        float nv = same ? -__builtin_inff() : s;
        if (diag) {
          int row_ = wr * 64 + r * 16 + quad * 4 + v;
          int col_ = wc * 64 + c * 16 + n16;
          if (row_ == col_) pv = __builtin_inff(); // exclude self from positives
        }
        int k = r * 4 + v;
        minp[k] = fminf(minp[k], pv);
        maxn[k] = fmaxf(maxn[k], nv);
        cminp[c] = fminf(cminp[c], same ? s : __builtin_inff());
        cmaxn[c] = fmaxf(cmaxn[c], same ? -__builtin_inff() : s);
      }
    }
  }

  // row-side: butterfly across the 16 n16-lanes sharing the same rows
#pragma unroll
  for (int m = 1; m <= 8; m <<= 1) {
#pragma unroll
    for (int k = 0; k < 16; ++k) {
      minp[k] = fminf(minp[k], __shfl_xor(minp[k], m, 64));
      maxn[k] = fmaxf(maxn[k], __shfl_xor(maxn[k], m, 64));
    }
  }
  if (n16 == 0) {
#pragma unroll
    for (int k = 0; k < 16; ++k) {
      int row = iBase + wr * 64 + (k >> 2) * 16 + quad * 4 + (k & 3);
      atomicMin(&minpos_enc[row], enc_f32(minp[k]));
      atomicMax(&maxneg_enc[row], enc_f32(maxn[k]));
    }
  }

  // col-side (transpose mining): butterfly across the 4 quads
  if (!diag) {
#pragma unroll
    for (int m = 16; m <= 32; m <<= 1) {
#pragma unroll
      for (int c = 0; c < 4; ++c) {
        cminp[c] = fminf(cminp[c], __shfl_xor(cminp[c], m, 64));
        cmaxn[c] = fmaxf(cmaxn[c], __shfl_xor(cmaxn[c], m, 64));
      }
    }
    if (quad == 0) {
#pragma unroll
      for (int c = 0; c < 4; ++c) {
        int row = jBase + wc * 64 + c * 16 + n16;
        atomicMin(&minpos_enc[row], enc_f32(cminp[c]));
        atomicMax(&maxneg_enc[row], enc_f32(cmaxn[c]));
      }
    }
  }
}

// ---- kernel 3: loss = mean(relu(maxneg_s - minpos_s + margin)) ----
__global__ __launch_bounds__(256) void finalize_loss(
    const int* __restrict__ minpos_enc, const int* __restrict__ maxneg_enc,
    float* __restrict__ out) {
  const int tid = threadIdx.x;
  const int4* mp4 = (const int4*)minpos_enc;
  const int4* mn4 = (const int4*)maxneg_enc;
  float sum = 0.f;
#pragma unroll
  for (int i = 0; i < 8; ++i) {
    int idx = i * 256 + tid; // 2048 int4 = 8192 entries
    int4 a = mp4[idx];
    int4 b = mn4[idx];
    const int* ap = (const int*)&a;
    const int* bp = (const int*)&b;
#pragma unroll
    for (int v = 0; v < 4; ++v) {
      float loss = dec_f32(bp[v]) - dec_f32(ap[v]) + MARGIN;
      sum += loss > 0.f ? loss : 0.f; // relu(-inf) = 0 matches jnp
    }
  }
#pragma unroll
  for (int m = 1; m < 64; m <<= 1) sum += __shfl_xor(sum, m, 64);
  __shared__ float ws4[4];
  const int lane = tid & 63, wave = tid >> 6;
  if (lane == 0) ws4[wave] = sum;
  __syncthreads();
  if (tid == 0) out[0] = (ws4[0] + ws4[1] + ws4[2] + ws4[3]) * (1.0f / N);
}

extern "C" void kernel_launch(void* const* d_in, const int* in_sizes, int n_in,
                              void* d_out, int out_size, void* d_ws, size_t ws_size,
                              hipStream_t stream) {
  const float* emb = (const float*)d_in[0];
  const int* labels = (const int*)d_in[1];
  float* out = (float*)d_out;

  unsigned short* e = (unsigned short*)d_ws; // N*D bf16 = 8 MB
  int* minpos_enc = (int*)((char*)d_ws + (size_t)N * D * sizeof(unsigned short));
  int* maxneg_enc = minpos_enc + N;

  normalize_rows<<<N / 4, 256, 0, stream>>>(emb, e, minpos_enc, maxneg_enc);
  bh_gemm_sym<<<dim3(NT, 33), 256, 0, stream>>>(e, labels, minpos_enc, maxneg_enc);
  finalize_loss<<<1, 256, 0, stream>>>(minpos_enc, maxneg_enc, out);
}